// Round 9
// baseline (231.835 us; speedup 1.0000x reference)
//
#include <hip/hip_runtime.h>
#include <math.h>

// X[8192,64], Y[8192,64] fp32.
// d2[i][j] = x2_i + y2_j - 2<x_i,y_j>;  out = mean_i sqrt(min_j d2) + mean_j sqrt(min_i d2)
//
// R9 = R5 (best: 85.0 us) + finish folded into mine as a tail-block pass.
//  - prep: fp32->bf16 + squares + zero ticket counter & out.
//  - mine: A register-persistent, B LDS double-buffered (register prefetch,
//    one barrier/chunk), 16x16x32 bf16 MFMA, epilogue tracks min(y2-2s) /
//    min(x2-2s) with x2/y2 folded into the slab partials. No atomics for
//    slabs: every slot written exactly once (0xAA-poison safe).
//  - tail: every block release-increments ticket; last 16 blocks spin to
//    counter==GRID (each increments before spinning -> no deadlock),
//    acquire-fence, reduce 1/16 shards of rslab+cslab, atomicAdd to out.
//    Cross-XCD visibility: __threadfence + acq_rel/acquire atomics (G16).
// Fixed floor: harness re-poisons the 268 MB d_ws inside the timed window
// (~41 us fill) — not controllable from here.

#define NROWS 8192
#define DDIM  64
#define ITILES 64
#define SLICES 16     // j: 16 slices x 512
#define CHUNKS 4      // 4 x 128 j per block
#define LSTR 72       // LDS row stride (bf16): 144 B, 16B-aligned rows
#define GRID (ITILES * SLICES)   // 1024
#define TAILS 16

typedef __bf16 bf16_t;
typedef bf16_t bf16x8 __attribute__((ext_vector_type(8)));
typedef float  f32x4  __attribute__((ext_vector_type(4)));

// ws: bf16 Xbf 1MB | Ybf 1MB | floats x2[8192] y2[8192] |
//     rslab[16][8192][2] 1MB | cslab[128][8192] 4MB | counter

__global__ void prep_kernel(const float* __restrict__ X,
                            const float* __restrict__ Y,
                            bf16_t* __restrict__ Xbf, bf16_t* __restrict__ Ybf,
                            float* __restrict__ x2, float* __restrict__ y2,
                            unsigned* __restrict__ counter,
                            float* __restrict__ out) {
  int t = blockIdx.x * blockDim.x + threadIdx.x;   // 0..65535
  int half = t >> 15;                              // 0: X, 1: Y
  int r = (t >> 2) & (NROWS - 1);
  int part = t & 3;                                // 16 elems per thread
  const float* src = half ? Y : X;
  bf16_t* dst = half ? Ybf : Xbf;
  float* sq = half ? y2 : x2;

  const float4* p = (const float4*)(src + r * DDIM + part * 16);
  float4 v0 = p[0], v1 = p[1], v2 = p[2], v3 = p[3];
  float s = 0.f;
  s = fmaf(v0.x, v0.x, s); s = fmaf(v0.y, v0.y, s);
  s = fmaf(v0.z, v0.z, s); s = fmaf(v0.w, v0.w, s);
  s = fmaf(v1.x, v1.x, s); s = fmaf(v1.y, v1.y, s);
  s = fmaf(v1.z, v1.z, s); s = fmaf(v1.w, v1.w, s);
  s = fmaf(v2.x, v2.x, s); s = fmaf(v2.y, v2.y, s);
  s = fmaf(v2.z, v2.z, s); s = fmaf(v2.w, v2.w, s);
  s = fmaf(v3.x, v3.x, s); s = fmaf(v3.y, v3.y, s);
  s = fmaf(v3.z, v3.z, s); s = fmaf(v3.w, v3.w, s);

  bf16x8 h0 = {(bf16_t)v0.x, (bf16_t)v0.y, (bf16_t)v0.z, (bf16_t)v0.w,
               (bf16_t)v1.x, (bf16_t)v1.y, (bf16_t)v1.z, (bf16_t)v1.w};
  bf16x8 h1 = {(bf16_t)v2.x, (bf16_t)v2.y, (bf16_t)v2.z, (bf16_t)v2.w,
               (bf16_t)v3.x, (bf16_t)v3.y, (bf16_t)v3.z, (bf16_t)v3.w};
  *(bf16x8*)&dst[r * DDIM + part * 16] = h0;
  *(bf16x8*)&dst[r * DDIM + part * 16 + 8] = h1;

  s += __shfl_xor(s, 1, 64);
  s += __shfl_xor(s, 2, 64);
  if (part == 0) sq[r] = s;
  if (t == 0) { out[0] = 0.f; *counter = 0u; }
}

__global__ __launch_bounds__(256, 2)
void mine_kernel(const bf16_t* __restrict__ Xbf, const bf16_t* __restrict__ Ybf,
                 const float* __restrict__ x2g, const float* __restrict__ y2g,
                 float* __restrict__ rslab, float* __restrict__ cslab,
                 unsigned* __restrict__ counter, float* __restrict__ out) {
  __shared__ bf16_t Ys[2][128 * LSTR];   // 2 x 18 KB
  __shared__ unsigned ticket_s;
  __shared__ float partial[4];

  const int tid = threadIdx.x;
  const int L = tid & 63;
  const int w = tid >> 6;
  const int lr = L & 15;
  const int q  = L >> 4;
  const int rh = w >> 1, ch = w & 1;
  const int itile = blockIdx.x & (ITILES - 1);
  const int slice = blockIdx.x >> 6;
  const int i0 = itile * 128;
  const int rgb = rh * 64, cgb = ch * 64;
  const int jbase = slice * (CHUNKS * 128);

  // ---- A fragments: register-persistent ----
  bf16x8 Af[8];
#pragma unroll
  for (int a = 0; a < 4; ++a) {
    int row = i0 + rgb + a * 16 + lr;
#pragma unroll
    for (int h = 0; h < 2; ++h)
      Af[a * 2 + h] = *(const bf16x8*)&Xbf[row * DDIM + h * 32 + q * 8];
  }
  float x2r[16];
#pragma unroll
  for (int a = 0; a < 4; ++a) {
    float4 v = *(const float4*)&x2g[i0 + rgb + a * 16 + q * 4];
    x2r[a * 4 + 0] = v.x; x2r[a * 4 + 1] = v.y;
    x2r[a * 4 + 2] = v.z; x2r[a * 4 + 3] = v.w;
  }
  float y2all[CHUNKS][4];
#pragma unroll
  for (int cc = 0; cc < CHUNKS; ++cc)
#pragma unroll
    for (int b = 0; b < 4; ++b)
      y2all[cc][b] = y2g[jbase + cc * 128 + cgb + b * 16 + lr];

  float rmin[16];
#pragma unroll
  for (int k = 0; k < 16; ++k) rmin[k] = INFINITY;

  // ---- prologue: stage chunk 0 ----
  bf16x8 Bst[4];
#pragma unroll
  for (int p = 0; p < 4; ++p) {
    int f = p * 256 + tid;
    Bst[p] = *(const bf16x8*)&Ybf[(jbase + (f >> 3)) * DDIM + (f & 7) * 8];
  }
#pragma unroll
  for (int p = 0; p < 4; ++p) {
    int f = p * 256 + tid;
    *(bf16x8*)&Ys[0][(f >> 3) * LSTR + (f & 7) * 8] = Bst[p];
  }
  __syncthreads();

  for (int cc = 0; cc < CHUNKS; ++cc) {
    const bf16_t* Yb = Ys[cc & 1];
    // issue next chunk's global loads now; latency hidden by compute
    if (cc + 1 < CHUNKS) {
      int j0n = jbase + (cc + 1) * 128;
#pragma unroll
      for (int p = 0; p < 4; ++p) {
        int f = p * 256 + tid;
        Bst[p] = *(const bf16x8*)&Ybf[(j0n + (f >> 3)) * DDIM + (f & 7) * 8];
      }
    }

    f32x4 acc[4][4];
#pragma unroll
    for (int a = 0; a < 4; ++a)
#pragma unroll
      for (int b = 0; b < 4; ++b) acc[a][b] = (f32x4){0.f, 0.f, 0.f, 0.f};

#pragma unroll
    for (int b = 0; b < 4; ++b) {
      bf16x8 B0 = *(const bf16x8*)&Yb[(cgb + b * 16 + lr) * LSTR + q * 8];
      bf16x8 B1 = *(const bf16x8*)&Yb[(cgb + b * 16 + lr) * LSTR + 32 + q * 8];
#pragma unroll
      for (int a = 0; a < 4; ++a) {
        acc[a][b] = __builtin_amdgcn_mfma_f32_16x16x32_bf16(Af[a * 2 + 0], B0, acc[a][b], 0, 0, 0);
        acc[a][b] = __builtin_amdgcn_mfma_f32_16x16x32_bf16(Af[a * 2 + 1], B1, acc[a][b], 0, 0, 0);
      }
    }

    // ---- epilogue (C/D: col = lr within 16-group, row = q*4+p) ----
    float cmin[4] = {INFINITY, INFINITY, INFINITY, INFINITY};
#pragma unroll
    for (int a = 0; a < 4; ++a)
#pragma unroll
      for (int p = 0; p < 4; ++p) {
        float x2v = x2r[a * 4 + p];
        float rm = rmin[a * 4 + p];
#pragma unroll
        for (int b = 0; b < 4; ++b) {
          float s = acc[a][b][p];
          rm = fminf(rm, fmaf(-2.f, s, y2all[cc][b]));
          cmin[b] = fminf(cmin[b], fmaf(-2.f, s, x2v));
        }
        rmin[a * 4 + p] = rm;
      }
#pragma unroll
    for (int b = 0; b < 4; ++b) {
      cmin[b] = fminf(cmin[b], __shfl_xor(cmin[b], 16, 64));
      cmin[b] = fminf(cmin[b], __shfl_xor(cmin[b], 32, 64));
    }
    float v = cmin[0], yv = y2all[cc][0];
    if (q == 1) { v = cmin[1]; yv = y2all[cc][1]; }
    else if (q == 2) { v = cmin[2]; yv = y2all[cc][2]; }
    else if (q == 3) { v = cmin[3]; yv = y2all[cc][3]; }
    cslab[(itile * 2 + rh) * NROWS + jbase + cc * 128 + cgb + L] = v + yv;

    // ---- write prefetched chunk into the other buffer, single barrier ----
    if (cc + 1 < CHUNKS) {
      bf16_t* Yn = Ys[(cc + 1) & 1];
#pragma unroll
      for (int p = 0; p < 4; ++p) {
        int f = p * 256 + tid;
        *(bf16x8*)&Yn[(f >> 3) * LSTR + (f & 7) * 8] = Bst[p];
      }
      __syncthreads();
    }
  }

  // ---- row mins: reduce across 16 col-lanes, fold x2, store once ----
#pragma unroll
  for (int a = 0; a < 4; ++a)
#pragma unroll
    for (int p = 0; p < 4; ++p) {
      float v = rmin[a * 4 + p];
      v = fminf(v, __shfl_xor(v, 1, 64));
      v = fminf(v, __shfl_xor(v, 2, 64));
      v = fminf(v, __shfl_xor(v, 4, 64));
      v = fminf(v, __shfl_xor(v, 8, 64));
      if (lr == 0)
        rslab[slice * (NROWS * 2) + (i0 + rgb + a * 16 + q * 4 + p) * 2 + ch] =
            v + x2r[a * 4 + p];
    }

  // ======== tail-block finish ========
  __threadfence();              // make slab stores device-visible (cross-XCD)
  __syncthreads();              // all waves' stores issued before ticket
  if (tid == 0)
    ticket_s = __hip_atomic_fetch_add(counter, 1u, __ATOMIC_ACQ_REL,
                                      __HIP_MEMORY_SCOPE_AGENT);
  __syncthreads();
  const unsigned ticket = ticket_s;
  if (ticket < GRID - TAILS) return;

  if (tid == 0) {
    while (__hip_atomic_load(counter, __ATOMIC_ACQUIRE,
                             __HIP_MEMORY_SCOPE_AGENT) < GRID)
      __builtin_amdgcn_s_sleep(8);
  }
  __syncthreads();
  __threadfence();

  const int shard = (int)(ticket - (GRID - TAILS));   // 0..15
  float sum = 0.f;
  // rows: 512 rows per shard
#pragma unroll
  for (int rr = 0; rr < 2; ++rr) {
    int row = shard * 512 + rr * 256 + tid;
    float m = INFINITY;
#pragma unroll
    for (int g = 0; g < SLICES; ++g) {
      float2 v = *(const float2*)&rslab[g * (NROWS * 2) + row * 2];
      m = fminf(m, fminf(v.x, v.y));
    }
    sum += sqrtf(fmaxf(m, 0.f));
  }
  // cols: 512 cols per shard
#pragma unroll
  for (int jj = 0; jj < 2; ++jj) {
    int j = shard * 512 + jj * 256 + tid;
    float m = INFINITY;
#pragma unroll 8
    for (int p = 0; p < 128; ++p) m = fminf(m, cslab[p * NROWS + j]);
    sum += sqrtf(fmaxf(m, 0.f));
  }
  sum *= (1.0f / 8192.0f);
#pragma unroll
  for (int off = 32; off > 0; off >>= 1) sum += __shfl_down(sum, off, 64);
  if ((tid & 63) == 0) partial[tid >> 6] = sum;
  __syncthreads();
  if (tid == 0)
    atomicAdd(out, partial[0] + partial[1] + partial[2] + partial[3]);
}

extern "C" void kernel_launch(void* const* d_in, const int* in_sizes, int n_in,
                              void* d_out, int out_size, void* d_ws, size_t ws_size,
                              hipStream_t stream) {
  const float* X = (const float*)d_in[0];
  const float* Y = (const float*)d_in[1];
  float* out = (float*)d_out;

  char* wsb = (char*)d_ws;
  bf16_t* Xbf = (bf16_t*)wsb;                                // 1 MB
  bf16_t* Ybf = (bf16_t*)(wsb + (size_t)NROWS * DDIM * 2);   // 1 MB
  float* x2 = (float*)(wsb + 2 * (size_t)NROWS * DDIM * 2);
  float* y2 = x2 + NROWS;
  float* rslab = y2 + NROWS;                    // [16][8192][2]  1 MB
  float* cslab = rslab + SLICES * NROWS * 2;    // [128][8192]    4 MB
  unsigned* counter = (unsigned*)(cslab + 128 * NROWS);

  prep_kernel<<<(2 * NROWS * 4) / 256, 256, 0, stream>>>(X, Y, Xbf, Ybf, x2, y2, counter, out);
  mine_kernel<<<GRID, 256, 0, stream>>>(Xbf, Ybf, x2, y2, rslab, cslab, counter, out);
}

// Round 10
// 86.210 us; speedup vs baseline: 2.6892x; 2.6892x over previous
//
#include <hip/hip_runtime.h>
#include <math.h>

// X[8192,64], Y[8192,64] fp32.
// d2[i][j] = x2_i + y2_j - 2<x_i,y_j>;  out = mean_i sqrt(min_j d2) + mean_j sqrt(min_i d2)
//
// R10 = R5 (best: 85.0 us) + register diet -> __launch_bounds__(256,3):
//  - x2r[16] -> x2acc[4] + __shfl at use (verified pattern, R7 passed).
//  - y2all[CHUNKS][4] -> y2c[4] loaded at chunk-loop top (consumed ~700 cyc
//    later in the epilogue; latency covered by the MFMA block).
//  Arch VGPR ~95-100 + 64 acc AGPR ≈ 164 <= 170 -> 3 waves/SIMD; LDS 36KB x 3
//  = 108KB <= 160. Goal: 3 staggered blocks/CU cover barrier + ds_read stalls
//  that 2 couldn't (R5 mine ~31 us vs ~5 us issue floor).
//  R9 lesson: NO per-block device fences (cross-XCD release = L2 writeback,
//  serializes the grid). Slabs: every slot written exactly once, no atomics.
// Fixed floor: harness re-poisons the 268 MB d_ws inside the timed window
// (~41 us fill) — not controllable from here.

#define NROWS 8192
#define DDIM  64
#define ITILES 64
#define SLICES 16     // j: 16 slices x 512
#define CHUNKS 4      // 4 x 128 j per block
#define LSTR 72       // LDS row stride (bf16): 144 B, 16B-aligned rows

typedef __bf16 bf16_t;
typedef bf16_t bf16x8 __attribute__((ext_vector_type(8)));
typedef float  f32x4  __attribute__((ext_vector_type(4)));

// ws: bf16 Xbf 1MB | Ybf 1MB | floats x2[8192] y2[8192] |
//     rslab[16][8192][2] 1MB | cslab[128][8192] 4MB

__global__ void prep_kernel(const float* __restrict__ X,
                            const float* __restrict__ Y,
                            bf16_t* __restrict__ Xbf, bf16_t* __restrict__ Ybf,
                            float* __restrict__ x2, float* __restrict__ y2,
                            float* __restrict__ out) {
  int t = blockIdx.x * blockDim.x + threadIdx.x;   // 0..65535
  int half = t >> 15;                              // 0: X, 1: Y
  int r = (t >> 2) & (NROWS - 1);
  int part = t & 3;                                // 16 elems per thread
  const float* src = half ? Y : X;
  bf16_t* dst = half ? Ybf : Xbf;
  float* sq = half ? y2 : x2;

  const float4* p = (const float4*)(src + r * DDIM + part * 16);
  float4 v0 = p[0], v1 = p[1], v2 = p[2], v3 = p[3];
  float s = 0.f;
  s = fmaf(v0.x, v0.x, s); s = fmaf(v0.y, v0.y, s);
  s = fmaf(v0.z, v0.z, s); s = fmaf(v0.w, v0.w, s);
  s = fmaf(v1.x, v1.x, s); s = fmaf(v1.y, v1.y, s);
  s = fmaf(v1.z, v1.z, s); s = fmaf(v1.w, v1.w, s);
  s = fmaf(v2.x, v2.x, s); s = fmaf(v2.y, v2.y, s);
  s = fmaf(v2.z, v2.z, s); s = fmaf(v2.w, v2.w, s);
  s = fmaf(v3.x, v3.x, s); s = fmaf(v3.y, v3.y, s);
  s = fmaf(v3.z, v3.z, s); s = fmaf(v3.w, v3.w, s);

  bf16x8 h0 = {(bf16_t)v0.x, (bf16_t)v0.y, (bf16_t)v0.z, (bf16_t)v0.w,
               (bf16_t)v1.x, (bf16_t)v1.y, (bf16_t)v1.z, (bf16_t)v1.w};
  bf16x8 h1 = {(bf16_t)v2.x, (bf16_t)v2.y, (bf16_t)v2.z, (bf16_t)v2.w,
               (bf16_t)v3.x, (bf16_t)v3.y, (bf16_t)v3.z, (bf16_t)v3.w};
  *(bf16x8*)&dst[r * DDIM + part * 16] = h0;
  *(bf16x8*)&dst[r * DDIM + part * 16 + 8] = h1;

  s += __shfl_xor(s, 1, 64);
  s += __shfl_xor(s, 2, 64);
  if (part == 0) sq[r] = s;
  if (t == 0) out[0] = 0.f;
}

__global__ __launch_bounds__(256, 3)
void mine_kernel(const bf16_t* __restrict__ Xbf, const bf16_t* __restrict__ Ybf,
                 const float* __restrict__ x2g, const float* __restrict__ y2g,
                 float* __restrict__ rslab, float* __restrict__ cslab) {
  __shared__ bf16_t Ys[2][128 * LSTR];   // 2 x 18 KB

  const int tid = threadIdx.x;
  const int L = tid & 63;
  const int w = tid >> 6;
  const int lr = L & 15;
  const int q  = L >> 4;
  const int rh = w >> 1, ch = w & 1;
  const int itile = blockIdx.x & (ITILES - 1);
  const int slice = blockIdx.x >> 6;
  const int i0 = itile * 128;
  const int rgb = rh * 64, cgb = ch * 64;
  const int jbase = slice * (CHUNKS * 128);

  // ---- A fragments: register-persistent ----
  bf16x8 Af[8];
#pragma unroll
  for (int a = 0; a < 4; ++a) {
    int row = i0 + rgb + a * 16 + lr;
#pragma unroll
    for (int h = 0; h < 2; ++h)
      Af[a * 2 + h] = *(const bf16x8*)&Xbf[row * DDIM + h * 32 + q * 8];
  }
  float x2acc[4];                       // x2 of row a*16+lr; shfl at use
#pragma unroll
  for (int a = 0; a < 4; ++a) x2acc[a] = x2g[i0 + rgb + a * 16 + lr];

  float rmin[16];
#pragma unroll
  for (int k = 0; k < 16; ++k) rmin[k] = INFINITY;

  // ---- prologue: stage chunk 0 ----
  bf16x8 Bst[4];
#pragma unroll
  for (int p = 0; p < 4; ++p) {
    int f = p * 256 + tid;
    Bst[p] = *(const bf16x8*)&Ybf[(jbase + (f >> 3)) * DDIM + (f & 7) * 8];
  }
#pragma unroll
  for (int p = 0; p < 4; ++p) {
    int f = p * 256 + tid;
    *(bf16x8*)&Ys[0][(f >> 3) * LSTR + (f & 7) * 8] = Bst[p];
  }
  __syncthreads();

  for (int cc = 0; cc < CHUNKS; ++cc) {
    const int j0 = jbase + cc * 128;
    const bf16_t* Yb = Ys[cc & 1];

    // y2 for this chunk: issued here, consumed ~700 cyc later in epilogue
    float y2c[4];
#pragma unroll
    for (int b = 0; b < 4; ++b) y2c[b] = y2g[j0 + cgb + b * 16 + lr];

    // issue next chunk's global loads now; latency hidden by compute
    if (cc + 1 < CHUNKS) {
      int j0n = j0 + 128;
#pragma unroll
      for (int p = 0; p < 4; ++p) {
        int f = p * 256 + tid;
        Bst[p] = *(const bf16x8*)&Ybf[(j0n + (f >> 3)) * DDIM + (f & 7) * 8];
      }
    }

    f32x4 acc[4][4];
#pragma unroll
    for (int a = 0; a < 4; ++a)
#pragma unroll
      for (int b = 0; b < 4; ++b) acc[a][b] = (f32x4){0.f, 0.f, 0.f, 0.f};

#pragma unroll
    for (int b = 0; b < 4; ++b) {
      bf16x8 B0 = *(const bf16x8*)&Yb[(cgb + b * 16 + lr) * LSTR + q * 8];
      bf16x8 B1 = *(const bf16x8*)&Yb[(cgb + b * 16 + lr) * LSTR + 32 + q * 8];
#pragma unroll
      for (int a = 0; a < 4; ++a) {
        acc[a][b] = __builtin_amdgcn_mfma_f32_16x16x32_bf16(Af[a * 2 + 0], B0, acc[a][b], 0, 0, 0);
        acc[a][b] = __builtin_amdgcn_mfma_f32_16x16x32_bf16(Af[a * 2 + 1], B1, acc[a][b], 0, 0, 0);
      }
    }

    // ---- epilogue (C/D: col = lr within 16-group, row = q*4+p) ----
    float cmin[4] = {INFINITY, INFINITY, INFINITY, INFINITY};
#pragma unroll
    for (int a = 0; a < 4; ++a)
#pragma unroll
      for (int p = 0; p < 4; ++p) {
        float x2v = __shfl(x2acc[a], q * 4 + p, 64);
        float rm = rmin[a * 4 + p];
#pragma unroll
        for (int b = 0; b < 4; ++b) {
          float s = acc[a][b][p];
          rm = fminf(rm, fmaf(-2.f, s, y2c[b]));
          cmin[b] = fminf(cmin[b], fmaf(-2.f, s, x2v));
        }
        rmin[a * 4 + p] = rm;
      }
#pragma unroll
    for (int b = 0; b < 4; ++b) {
      cmin[b] = fminf(cmin[b], __shfl_xor(cmin[b], 16, 64));
      cmin[b] = fminf(cmin[b], __shfl_xor(cmin[b], 32, 64));
    }
    float v = cmin[0], yv = y2c[0];
    if (q == 1) { v = cmin[1]; yv = y2c[1]; }
    else if (q == 2) { v = cmin[2]; yv = y2c[2]; }
    else if (q == 3) { v = cmin[3]; yv = y2c[3]; }
    cslab[(itile * 2 + rh) * NROWS + j0 + cgb + L] = v + yv;  // y2 folded

    // ---- write prefetched chunk into the other buffer, single barrier ----
    if (cc + 1 < CHUNKS) {
      bf16_t* Yn = Ys[(cc + 1) & 1];
#pragma unroll
      for (int p = 0; p < 4; ++p) {
        int f = p * 256 + tid;
        *(bf16x8*)&Yn[(f >> 3) * LSTR + (f & 7) * 8] = Bst[p];
      }
      __syncthreads();
    }
  }

  // ---- row mins: reduce across 16 col-lanes, fold x2, store once ----
#pragma unroll
  for (int a = 0; a < 4; ++a)
#pragma unroll
    for (int p = 0; p < 4; ++p) {
      float v = rmin[a * 4 + p];
      v = fminf(v, __shfl_xor(v, 1, 64));
      v = fminf(v, __shfl_xor(v, 2, 64));
      v = fminf(v, __shfl_xor(v, 4, 64));
      v = fminf(v, __shfl_xor(v, 8, 64));
      float x2v = __shfl(x2acc[a], q * 4 + p, 64);
      if (lr == 0)
        rslab[slice * (NROWS * 2) + (i0 + rgb + a * 16 + q * 4 + p) * 2 + ch] =
            v + x2v;
    }
}

// blocks [0,32): rows (256 each, coalesced float2). [32,160): cols (64 each,
// 4 segments x 32 partials, LDS combine). Slab values already include x2/y2.
__global__ void finish_kernel(const float* __restrict__ rslab,
                              const float* __restrict__ cslab,
                              float* __restrict__ out) {
  const int b = blockIdx.x;
  const int tid = threadIdx.x;
  if (b < 32) {
    int row = b * 256 + tid;
    float m = INFINITY;
#pragma unroll
    for (int g = 0; g < SLICES; ++g) {
      float2 v = *(const float2*)&rslab[g * (NROWS * 2) + row * 2];
      m = fminf(m, fminf(v.x, v.y));
    }
    float v = sqrtf(fmaxf(m, 0.f)) * (1.0f / 8192.0f);
#pragma unroll
    for (int off = 32; off > 0; off >>= 1) v += __shfl_down(v, off, 64);
    __shared__ float partial[4];
    if ((tid & 63) == 0) partial[tid >> 6] = v;
    __syncthreads();
    if (tid == 0)
      atomicAdd(out, partial[0] + partial[1] + partial[2] + partial[3]);
  } else {
    int j = (b - 32) * 64 + (tid & 63);
    int seg = tid >> 6;
    float m = INFINITY;
#pragma unroll
    for (int k = 0; k < 32; ++k)
      m = fminf(m, cslab[(seg * 32 + k) * NROWS + j]);
    __shared__ float red[4][64];
    red[seg][tid & 63] = m;
    __syncthreads();
    if (tid < 64) {
      float mc = fminf(fminf(red[0][tid], red[1][tid]),
                       fminf(red[2][tid], red[3][tid]));
      float v = sqrtf(fmaxf(mc, 0.f)) * (1.0f / 8192.0f);
#pragma unroll
      for (int off = 32; off > 0; off >>= 1) v += __shfl_down(v, off, 64);
      if (tid == 0) atomicAdd(out, v);
    }
  }
}

extern "C" void kernel_launch(void* const* d_in, const int* in_sizes, int n_in,
                              void* d_out, int out_size, void* d_ws, size_t ws_size,
                              hipStream_t stream) {
  const float* X = (const float*)d_in[0];
  const float* Y = (const float*)d_in[1];
  float* out = (float*)d_out;

  char* wsb = (char*)d_ws;
  bf16_t* Xbf = (bf16_t*)wsb;                                // 1 MB
  bf16_t* Ybf = (bf16_t*)(wsb + (size_t)NROWS * DDIM * 2);   // 1 MB
  float* x2 = (float*)(wsb + 2 * (size_t)NROWS * DDIM * 2);
  float* y2 = x2 + NROWS;
  float* rslab = y2 + NROWS;                    // [16][8192][2]  1 MB
  float* cslab = rslab + SLICES * NROWS * 2;    // [128][8192]    4 MB

  prep_kernel<<<(2 * NROWS * 4) / 256, 256, 0, stream>>>(X, Y, Xbf, Ybf, x2, y2, out);
  mine_kernel<<<ITILES * SLICES, 256, 0, stream>>>(Xbf, Ybf, x2, y2, rslab, cslab);
  finish_kernel<<<160, 256, 0, stream>>>(rslab, cslab, out);
}